// Round 1
// baseline (954.565 us; speedup 1.0000x reference)
//
#include <hip/hip_runtime.h>
#include <math.h>

// Problem dims (fixed by setup_inputs): inp [1,2,48,160,160] f32, target [1,48,160,160] i32
#define D_ 48
#define H_ 160
#define W_ 160
#define HW_ 25600
#define N_ 1228800
#define NBLK 4800          // N_/256
#define K1_ 1216512u       // 1-based rank of sorted index 1216511 (= floor(0.99*(N-1)))
#define K2_ 1216513u       // next order statistic

static_assert(N_ == D_ * HW_, "dims");
static_assert(N_ == NBLK * 256, "grid");

// ---- workspace layout (bytes) ----
#define OFF_KL  0u
#define OFF_FA  (N_ * 4u)
#define OFF_FB  (2u * N_ * 4u)
#define OFF_H1  (3u * N_ * 4u)
#define OFF_HA  (OFF_H1 + 65536u * 4u)
#define OFF_HB  (OFF_HA + 65536u * 4u)
#define OFF_SC  (OFF_HB + 65536u * 4u)   // 16 u32 scalars
#define OFF_PS  (OFF_SC + 64u)
#define OFF_PC  (OFF_PS + NBLK * 4u)
#define WS_NEED (OFF_PC + NBLK * 4u)
// scalars: sc[0]=bktA sc[1]=rnkA sc[2]=bktB sc[3]=rnkB sc[4]=vA bits sc[5]=vB bits sc[6]=thr bits

__device__ __forceinline__ unsigned fkey(float v) {
  unsigned u = __float_as_uint(v);
  return (u & 0x80000000u) ? ~u : (u | 0x80000000u);  // monotone map: float asc -> uint asc
}

// ---------------- kernel 1: kl_vals + initial squared-dist field ----------------
__global__ __launch_bounds__(256) void k_prep(const float* __restrict__ inp,
                                              const int* __restrict__ tgt,
                                              float* __restrict__ kl,
                                              float* __restrict__ f0) {
  const int idx = blockIdx.x * 256 + threadIdx.x;
  const int ww = idx % W_;
  const int hh = (idx / W_) % H_;
  const int dd = idx / HW_;
  const float p0 = inp[idx];
  const float p1 = inp[N_ + idx];

  float klh = -1.0f, klv = -1.0f, kld = -1.0f;
  if (ww < W_ - 1) {
    const float t0 = inp[idx + 1], t1 = inp[N_ + idx + 1];
    const float a0 = (t0 > 0.f) ? t0 * logf(t0) : 0.f;
    const float a1 = (t1 > 0.f) ? t1 * logf(t1) : 0.f;
    klh = 0.5f * ((a0 - t0 * p0) + (a1 - t1 * p1));
  }
  if (hh < H_ - 1) {
    const float t0 = inp[idx + W_], t1 = inp[N_ + idx + W_];
    const float a0 = (t0 > 0.f) ? t0 * logf(t0) : 0.f;
    const float a1 = (t1 > 0.f) ? t1 * logf(t1) : 0.f;
    klv = 0.5f * ((a0 - t0 * p0) + (a1 - t1 * p1));
  }
  if (dd < D_ - 1) {
    const float t0 = inp[idx + HW_], t1 = inp[N_ + idx + HW_];
    const float a0 = (t0 > 0.f) ? t0 * logf(t0) : 0.f;
    const float a1 = (t1 > 0.f) ? t1 * logf(t1) : 0.f;
    kld = 0.5f * ((a0 - t0 * p0) + (a1 - t1 * p1));
  }
  kl[idx] = fmaxf(fmaxf(klh, klv), kld);

  const int tv = tgt[idx];
  const int t1 = (ww < W_ - 1) ? tgt[idx + 1] : 0;
  const int t2 = (hh < H_ - 1) ? tgt[idx + W_] : 0;
  const int t3 = (dd < D_ - 1) ? tgt[idx + HW_] : 0;
  f0[idx] = (3 * tv != t1 + t2 + t3) ? 0.f : 1e10f;
}

// ---------------- EDT pass along D (tiled, coalesced) ----------------
__global__ __launch_bounds__(256) void k_dt_d(const float* __restrict__ fin,
                                              float* __restrict__ fout) {
  __shared__ float lds[D_][256];
  const int tid = threadIdx.x;
  const int col = blockIdx.x * 256 + tid;  // 0..HW_-1, grid.x = HW_/256
  for (int j = 0; j < D_; j++) lds[j][tid] = fin[j * HW_ + col];
  __syncthreads();
  const int d0 = blockIdx.y * (D_ / 4);
  for (int dd = d0; dd < d0 + (D_ / 4); dd++) {
    float m = lds[0][tid] + (float)(dd * dd);
    for (int j = 1; j < D_; j++) {
      const int q = dd - j;
      m = fminf(m, lds[j][tid] + (float)(q * q));
    }
    fout[dd * HW_ + col] = m;
  }
}

// ---------------- EDT pass along H (line per block) ----------------
__global__ void k_dt_h(const float* __restrict__ fin, float* __restrict__ fout) {
  __shared__ float line[H_];
  const int b = blockIdx.x;        // 0 .. D_*W_-1
  const int dd = b / W_;
  const int ww = b - dd * W_;
  const int t = threadIdx.x;       // 0..H_-1
  line[t] = fin[dd * HW_ + t * W_ + ww];
  __syncthreads();
  float m = line[0] + (float)(t * t);
  for (int j = 1; j < H_; j++) {
    const int q = t - j;
    m = fminf(m, line[j] + (float)(q * q));
  }
  fout[dd * HW_ + t * W_ + ww] = m;
}

// ---------------- EDT pass along W (line per block) + sqrt ----------------
__global__ void k_dt_w(const float* __restrict__ fin, float* __restrict__ fout) {
  __shared__ float line[W_];
  const int base = blockIdx.x * W_;  // blockIdx over D_*H_ rows
  const int t = threadIdx.x;         // 0..W_-1
  line[t] = fin[base + t];
  __syncthreads();
  float m = line[0] + (float)(t * t);
  for (int j = 1; j < W_; j++) {
    const int q = t - j;
    m = fminf(m, line[j] + (float)(q * q));
  }
  fout[base + t] = sqrtf(m);
}

// ---------------- quantile: high-16 histogram ----------------
__global__ __launch_bounds__(256) void k_hist_hi(const float* __restrict__ kl,
                                                 unsigned* __restrict__ hist) {
  const int idx = blockIdx.x * 256 + threadIdx.x;
  atomicAdd(&hist[fkey(kl[idx]) >> 16], 1u);
}

// find bucket containing rank K; write bucket + rank-within-bucket
__global__ __launch_bounds__(256) void k_sel_hi(const unsigned* __restrict__ hist, unsigned K,
                                                unsigned* __restrict__ outB,
                                                unsigned* __restrict__ outR) {
  __shared__ unsigned ssum[256];
  __shared__ unsigned spre[256];
  const int t = threadIdx.x;
  unsigned s = 0;
  for (int i = 0; i < 256; i++) s += hist[t * 256 + i];
  ssum[t] = s;
  __syncthreads();
  if (t == 0) {
    unsigned c = 0;
    for (int i = 0; i < 256; i++) { spre[i] = c; c += ssum[i]; }
  }
  __syncthreads();
  const unsigned before = spre[t];
  if (before < K && K <= before + ssum[t]) {
    unsigned cum = before;
    for (int i = 0; i < 256; i++) {
      const unsigned c = hist[t * 256 + i];
      if (cum < K && K <= cum + c) { *outB = (unsigned)(t * 256 + i); *outR = K - cum; break; }
      cum += c;
    }
  }
}

// low-16 histograms for both target buckets
__global__ __launch_bounds__(256) void k_hist_lo(const float* __restrict__ kl,
                                                 const unsigned* __restrict__ sc,
                                                 unsigned* __restrict__ histA,
                                                 unsigned* __restrict__ histB) {
  const int idx = blockIdx.x * 256 + threadIdx.x;
  const unsigned key = fkey(kl[idx]);
  const unsigned hi = key >> 16;
  if (hi == sc[0]) atomicAdd(&histA[key & 0xFFFFu], 1u);
  if (hi == sc[2]) atomicAdd(&histB[key & 0xFFFFu], 1u);
}

// find exact low bits for rank within bucket; write value bits
__global__ __launch_bounds__(256) void k_sel_lo(const unsigned* __restrict__ hist,
                                                const unsigned* __restrict__ bktPtr,
                                                const unsigned* __restrict__ rnkPtr,
                                                unsigned* __restrict__ outBits) {
  __shared__ unsigned ssum[256];
  __shared__ unsigned spre[256];
  const int t = threadIdx.x;
  const unsigned K = *rnkPtr;
  unsigned s = 0;
  for (int i = 0; i < 256; i++) s += hist[t * 256 + i];
  ssum[t] = s;
  __syncthreads();
  if (t == 0) {
    unsigned c = 0;
    for (int i = 0; i < 256; i++) { spre[i] = c; c += ssum[i]; }
  }
  __syncthreads();
  const unsigned before = spre[t];
  if (before < K && K <= before + ssum[t]) {
    unsigned cum = before;
    for (int i = 0; i < 256; i++) {
      const unsigned c = hist[t * 256 + i];
      if (cum < K && K <= cum + c) {
        const unsigned key = ((*bktPtr) << 16) | (unsigned)(t * 256 + i);
        *outBits = (key & 0x80000000u) ? (key & 0x7FFFFFFFu) : ~key;  // inverse of fkey
        break;
      }
      cum += c;
    }
  }
}

// thr exactly as jnp.quantile in f32: index=0.99*(N-1) rounds so frac==0 -> thr = v_lo
__global__ void k_thr(unsigned* sc) {
  const float vA = __uint_as_float(sc[4]);
  const float vB = __uint_as_float(sc[5]);
  const float vi = 0.99f * (float)(N_ - 1);
  const float frac = vi - floorf(vi);           // == 0 in f32, kept general
  sc[6] = __float_as_uint(vA * (1.f - frac) + vB * frac);
}

// ---------------- masked loss at each voxel + block partials ----------------
__global__ __launch_bounds__(256) void k_loss(const float* __restrict__ inp,
                                              const float* __restrict__ kl,
                                              const float* __restrict__ gdist,
                                              const unsigned* __restrict__ sc,
                                              float* __restrict__ psum,
                                              unsigned* __restrict__ pcnt) {
  const int tid = threadIdx.x;
  const int idx = blockIdx.x * 256 + tid;
  const float thr = __uint_as_float(sc[6]);
  float myloss = 0.f;
  unsigned mycnt = 0u;
  if (kl[idx] >= thr) {
    mycnt = 1u;
    const float g = gdist[idx];
    if (g != 0.f) {
      const int ww = idx % W_;
      const int hh = (idx / W_) % H_;
      const int dd = idx / HW_;
      const float p0 = inp[idx];
      const float p1 = inp[N_ + idx];
      // DIRECTIONS in torch-loop order: i outer, j mid, k inner, skipping (0,0,0)
      constexpr int DI[26] = {-1,-1,-1,-1,-1,-1,-1,-1,-1, 0,0,0,0,0,0,0,0, 1,1,1,1,1,1,1,1,1};
      constexpr int DJ[26] = {-1,-1,-1, 0,0,0, 1,1,1, -1,-1,-1, 0,0, 1,1,1, -1,-1,-1, 0,0,0, 1,1,1};
      constexpr int DK[26] = {-1,0,1, -1,0,1, -1,0,1, -1,0,1, -1,1, -1,0,1, -1,0,1, -1,0,1, -1,0,1};
      float klv[26], dst[26];
      float s = 0.f;
#pragma unroll
      for (int t = 0; t < 26; t++) {
        const int nd = dd + DI[t], nh = hh + DJ[t], nw = ww + DK[t];
        const bool inb = ((unsigned)nd < (unsigned)D_) && ((unsigned)nh < (unsigned)H_) &&
                         ((unsigned)nw < (unsigned)W_);
        const int nidx = (nd * H_ + nh) * W_ + nw;
        dst[t] = inb ? gdist[nidx] : 0.f;
        // coordinate masks from the reference's (batch,d,h) indexing bug, specialized to B=1:
        //  i==+1 -> 0 (batch never 47); j==+1 -> 0 (d never 159); j==-1 -> only d==0;
        //  k==+1 -> only h==159; k==-1 -> only h==0
        bool keep;
        if (DI[t] == 1 || DJ[t] == 1) keep = false;
        else {
          keep = true;
          if (DJ[t] == -1) keep = (dd == 0);
          if (DK[t] == 1) keep = keep && (hh == H_ - 1);
          if (DK[t] == -1) keep = keep && (hh == 0);
        }
        float kt = 0.f;
        if (keep) {
          float t0 = 0.f, t1 = 0.f;
          if (inb) { t0 = inp[nidx]; t1 = inp[N_ + nidx]; }
          const float a0 = (t0 > 0.f) ? t0 * logf(t0) : 0.f;
          const float a1 = (t1 > 0.f) ? t1 * logf(t1) : 0.f;
          const float kldm = 0.5f * ((a0 - t0 * p0) + (a1 - t1 * p1));
          kt = expf(kldm);
        }
        klv[t] = kt;
        s += kt;
      }
      const float denom = (s == 0.f) ? 1.f : s;
      int amin = 0;
      float dmin = dst[0];
#pragma unroll
      for (int t = 1; t < 26; t++) {
        if (dst[t] < dmin) { dmin = dst[t]; amin = t; }  // first-min, like jnp.argmin
      }
      const float yoff = (float)(0.2 / 26.0);
      float bsum = 0.f;
#pragma unroll
      for (int t = 0; t < 26; t++) {
        const float x = klv[t] / denom;
        const float y = (t == amin) ? 0.8f : yoff;
        bsum += fmaxf(x, 0.f) - x * y + log1pf(expf(-fabsf(x)));
      }
      myloss = (fminf(g, 20.f) / 20.f) * (bsum / 26.f);
    }
  }
  __shared__ float ls[256];
  __shared__ unsigned lc[256];
  ls[tid] = myloss;
  lc[tid] = mycnt;
  __syncthreads();
  for (int o = 128; o > 0; o >>= 1) {
    if (tid < o) { ls[tid] += ls[tid + o]; lc[tid] += lc[tid + o]; }
    __syncthreads();
  }
  if (tid == 0) { psum[blockIdx.x] = ls[0]; pcnt[blockIdx.x] = lc[0]; }
}

// ---------------- deterministic final reduce ----------------
__global__ __launch_bounds__(256) void k_reduce(const float* __restrict__ psum,
                                                const unsigned* __restrict__ pcnt,
                                                float* __restrict__ out) {
  __shared__ float ls[256];
  __shared__ unsigned lc[256];
  const int t = threadIdx.x;
  float s = 0.f;
  unsigned c = 0;
  for (int i = t; i < NBLK; i += 256) { s += psum[i]; c += pcnt[i]; }
  ls[t] = s;
  lc[t] = c;
  __syncthreads();
  for (int o = 128; o > 0; o >>= 1) {
    if (t < o) { ls[t] += ls[t + o]; lc[t] += lc[t + o]; }
    __syncthreads();
  }
  if (t == 0) out[0] = ls[0] / (float)lc[0];
}

extern "C" void kernel_launch(void* const* d_in, const int* in_sizes, int n_in,
                              void* d_out, int out_size, void* d_ws, size_t ws_size,
                              hipStream_t stream) {
  (void)in_sizes; (void)n_in; (void)out_size; (void)ws_size;
  const float* inp = (const float*)d_in[0];
  const int* tgt = (const int*)d_in[1];
  float* out = (float*)d_out;
  char* ws = (char*)d_ws;

  float* kl = (float*)(ws + OFF_KL);
  float* fA = (float*)(ws + OFF_FA);
  float* fB = (float*)(ws + OFF_FB);
  unsigned* h1 = (unsigned*)(ws + OFF_H1);
  unsigned* hA = (unsigned*)(ws + OFF_HA);
  unsigned* hB = (unsigned*)(ws + OFF_HB);
  unsigned* sc = (unsigned*)(ws + OFF_SC);
  float* ps = (float*)(ws + OFF_PS);
  unsigned* pc = (unsigned*)(ws + OFF_PC);

  // zero the three histograms (contiguous region)
  hipMemsetAsync(h1, 0, 3u * 65536u * 4u, stream);

  k_prep<<<NBLK, 256, 0, stream>>>(inp, tgt, kl, fA);
  k_dt_d<<<dim3(HW_ / 256, 4), 256, 0, stream>>>(fA, fB);
  k_dt_h<<<D_ * W_, H_, 0, stream>>>(fB, fA);
  k_dt_w<<<D_ * H_, W_, 0, stream>>>(fA, fB);  // fB = gdb_dist (sqrt applied)

  k_hist_hi<<<NBLK, 256, 0, stream>>>(kl, h1);
  k_sel_hi<<<1, 256, 0, stream>>>(h1, K1_, sc + 0, sc + 1);
  k_sel_hi<<<1, 256, 0, stream>>>(h1, K2_, sc + 2, sc + 3);
  k_hist_lo<<<NBLK, 256, 0, stream>>>(kl, sc, hA, hB);
  k_sel_lo<<<1, 256, 0, stream>>>(hA, sc + 0, sc + 1, sc + 4);
  k_sel_lo<<<1, 256, 0, stream>>>(hB, sc + 2, sc + 3, sc + 5);
  k_thr<<<1, 1, 0, stream>>>(sc);

  k_loss<<<NBLK, 256, 0, stream>>>(inp, kl, fB, sc, ps, pc);
  k_reduce<<<1, 256, 0, stream>>>(ps, pc, out);
}

// Round 2
// 99.168 us; speedup vs baseline: 9.6258x; 9.6258x over previous
//
#include <hip/hip_runtime.h>
#include <math.h>

// Problem dims (fixed by setup_inputs): inp [1,2,48,160,160] f32, target [1,48,160,160] i32
#define D_ 48
#define H_ 160
#define W_ 160
#define HW_ 25600
#define N_ 1228800
#define NBLK 4800          // N_/256
#define HBLK 600           // histogram-pass blocks (8 elems/thread)
#define K1_ 1216512u       // 1-based rank of sorted index 1216511 (= floor(0.99*(N-1)); frac==0 in f32)

static_assert(N_ == D_ * HW_, "dims");
static_assert(N_ == NBLK * 256, "grid");
static_assert(N_ == HBLK * 256 * 8, "hist grid");

// ---- workspace layout (bytes) ----
#define OFF_KL  0u
#define OFF_FA  (N_ * 4u)
#define OFF_FB  (2u * N_ * 4u)
#define OFF_G1  (3u * N_ * 4u)            // 4096 u32
#define OFF_G2  (OFF_G1 + 4096u * 4u)     // 4096 u32
#define OFF_G3  (OFF_G2 + 4096u * 4u)     // 256 u32
#define OFF_SC  (OFF_G3 + 256u * 4u)      // 16 u32 scalars
#define OFF_PS  (OFF_SC + 64u)
#define OFF_PC  (OFF_PS + NBLK * 4u)
#define ZERO_BYTES ((4096u + 4096u + 256u + 16u) * 4u)
// scalars: sc[0]=b1 sc[1]=rank1 sc[2]=b2 sc[3]=rank2 sc[4]=b3 sc[5]=rank3 sc[6]=thr bits

__device__ __forceinline__ unsigned fkey(float v) {
  unsigned u = __float_as_uint(v);
  return (u & 0x80000000u) ? ~u : (u | 0x80000000u);  // monotone map: float asc -> uint asc
}

// ---------------- kernel 1: kl_vals + initial dist field + level-1 (hi-12) histogram ----------------
__global__ __launch_bounds__(256) void k_prep(const float* __restrict__ inp,
                                              const int* __restrict__ tgt,
                                              float* __restrict__ kl,
                                              float* __restrict__ f0,
                                              unsigned* __restrict__ ghist) {
  __shared__ unsigned h[4096];
  const int tid = threadIdx.x;
  for (int i = tid; i < 4096; i += 256) h[i] = 0;
  __syncthreads();
  const int base = blockIdx.x * 2048;
  for (int e = 0; e < 8; e++) {
    const int idx = base + e * 256 + tid;
    const int ww = idx % W_;
    const int hh = (idx / W_) % H_;
    const int dd = idx / HW_;
    const float p0 = inp[idx];
    const float p1 = inp[N_ + idx];

    float klh = -1.0f, klv = -1.0f, kld = -1.0f;
    if (ww < W_ - 1) {
      const float t0 = inp[idx + 1], t1 = inp[N_ + idx + 1];
      const float a0 = (t0 > 0.f) ? t0 * logf(t0) : 0.f;
      const float a1 = (t1 > 0.f) ? t1 * logf(t1) : 0.f;
      klh = 0.5f * ((a0 - t0 * p0) + (a1 - t1 * p1));
    }
    if (hh < H_ - 1) {
      const float t0 = inp[idx + W_], t1 = inp[N_ + idx + W_];
      const float a0 = (t0 > 0.f) ? t0 * logf(t0) : 0.f;
      const float a1 = (t1 > 0.f) ? t1 * logf(t1) : 0.f;
      klv = 0.5f * ((a0 - t0 * p0) + (a1 - t1 * p1));
    }
    if (dd < D_ - 1) {
      const float t0 = inp[idx + HW_], t1 = inp[N_ + idx + HW_];
      const float a0 = (t0 > 0.f) ? t0 * logf(t0) : 0.f;
      const float a1 = (t1 > 0.f) ? t1 * logf(t1) : 0.f;
      kld = 0.5f * ((a0 - t0 * p0) + (a1 - t1 * p1));
    }
    const float kmax = fmaxf(fmaxf(klh, klv), kld);
    kl[idx] = kmax;
    atomicAdd(&h[fkey(kmax) >> 20], 1u);

    const int tv = tgt[idx];
    const int t1 = (ww < W_ - 1) ? tgt[idx + 1] : 0;
    const int t2 = (hh < H_ - 1) ? tgt[idx + W_] : 0;
    const int t3 = (dd < D_ - 1) ? tgt[idx + HW_] : 0;
    f0[idx] = (3 * tv != t1 + t2 + t3) ? 0.f : 1e10f;
  }
  __syncthreads();
  for (int i = tid; i < 4096; i += 256) {
    const unsigned c = h[i];
    if (c) atomicAdd(&ghist[i], c);
  }
}

// ---------------- EDT pass along one axis, early-exit outward scan (bit-exact) ----------------
// min over all j of f[j]+(i-j)^2: since f>=0, RN(f[j]+r^2) >= r^2, so once r^2 >= m no further
// candidate can lower the min; min over a set is order-independent -> identical bits vs brute force.
template <int STRIDE, int LEN, int AXIS, bool DOSQRT>
__global__ __launch_bounds__(256) void k_dt(const float* __restrict__ fin,
                                            float* __restrict__ fout) {
  const int idx = blockIdx.x * 256 + threadIdx.x;
  const int pos = (AXIS == 0) ? (idx / HW_) : ((AXIS == 1) ? ((idx / W_) % H_) : (idx % W_));
  float m = fin[idx];
  for (int r = 1; r < LEN; r++) {
    const float r2 = (float)(r * r);
    if (r2 >= m) break;
    const int jm = pos - r, jp = pos + r;
    const bool okm = (jm >= 0), okp = (jp < LEN);
    if (!okm && !okp) break;
    if (okm) m = fminf(m, fin[idx - r * STRIDE] + r2);
    if (okp) m = fminf(m, fin[idx + r * STRIDE] + r2);
  }
  fout[idx] = DOSQRT ? sqrtf(m) : m;
}

// ---------------- generic rank-select over a histogram (nb = 256*chunk buckets) ----------------
__global__ __launch_bounds__(256) void k_sel(const unsigned* __restrict__ hist, int nb,
                                             const unsigned* __restrict__ Kp, unsigned Kimm,
                                             unsigned* __restrict__ outB,
                                             unsigned* __restrict__ outR) {
  __shared__ unsigned ssum[256];
  __shared__ unsigned spre[256];
  const int t = threadIdx.x;
  const unsigned K = Kp ? *Kp : Kimm;
  const int chunk = nb >> 8;
  unsigned s = 0;
  for (int i = 0; i < chunk; i++) s += hist[t * chunk + i];
  ssum[t] = s;
  __syncthreads();
  if (t == 0) {
    unsigned c = 0;
    for (int i = 0; i < 256; i++) { spre[i] = c; c += ssum[i]; }
  }
  __syncthreads();
  const unsigned before = spre[t];
  if (before < K && K <= before + ssum[t]) {
    unsigned cum = before;
    for (int i = 0; i < chunk; i++) {
      const unsigned c = hist[t * chunk + i];
      if (cum < K && K <= cum + c) { *outB = (unsigned)(t * chunk + i); *outR = K - cum; break; }
      cum += c;
    }
  }
}

// ---------------- level-2 histogram: mid-12 bits within selected hi-12 bucket ----------------
__global__ __launch_bounds__(256) void k_hist2(const float* __restrict__ kl,
                                               const unsigned* __restrict__ sc,
                                               unsigned* __restrict__ ghist) {
  __shared__ unsigned h[4096];
  const int tid = threadIdx.x;
  for (int i = tid; i < 4096; i += 256) h[i] = 0;
  __syncthreads();
  const unsigned b1 = sc[0];
  const int base = blockIdx.x * 2048;
  for (int e = 0; e < 8; e++) {
    const int idx = base + e * 256 + tid;
    const unsigned key = fkey(kl[idx]);
    if ((key >> 20) == b1) atomicAdd(&h[(key >> 8) & 0xFFFu], 1u);
  }
  __syncthreads();
  for (int i = tid; i < 4096; i += 256) {
    const unsigned c = h[i];
    if (c) atomicAdd(&ghist[i], c);
  }
}

// ---------------- level-3 histogram: low-8 bits within selected hi-24 prefix ----------------
__global__ __launch_bounds__(256) void k_hist3(const float* __restrict__ kl,
                                               const unsigned* __restrict__ sc,
                                               unsigned* __restrict__ ghist) {
  __shared__ unsigned h[256];
  const int tid = threadIdx.x;
  h[tid] = 0;
  __syncthreads();
  const unsigned hi24 = (sc[0] << 12) | sc[2];
  const int base = blockIdx.x * 2048;
  for (int e = 0; e < 8; e++) {
    const int idx = base + e * 256 + tid;
    const unsigned key = fkey(kl[idx]);
    if ((key >> 8) == hi24) atomicAdd(&h[key & 0xFFu], 1u);
  }
  __syncthreads();
  const unsigned c = h[tid];
  if (c) atomicAdd(&ghist[tid], c);
}

// thr = order statistic at rank K1 (frac term is exactly 0, verified bit-exact in R1)
__global__ void k_thr(unsigned* sc) {
  const unsigned key = (sc[0] << 20) | (sc[2] << 8) | sc[4];
  sc[6] = (key & 0x80000000u) ? (key & 0x7FFFFFFFu) : ~key;  // inverse of fkey
}

// ---------------- masked loss at each voxel + block partials ----------------
__global__ __launch_bounds__(256) void k_loss(const float* __restrict__ inp,
                                              const float* __restrict__ kl,
                                              const float* __restrict__ gdist,
                                              const unsigned* __restrict__ sc,
                                              float* __restrict__ psum,
                                              unsigned* __restrict__ pcnt) {
  const int tid = threadIdx.x;
  const int idx = blockIdx.x * 256 + tid;
  const float thr = __uint_as_float(sc[6]);
  float myloss = 0.f;
  unsigned mycnt = 0u;
  if (kl[idx] >= thr) {
    mycnt = 1u;
    const float g = gdist[idx];
    if (g != 0.f) {
      const int ww = idx % W_;
      const int hh = (idx / W_) % H_;
      const int dd = idx / HW_;
      const float p0 = inp[idx];
      const float p1 = inp[N_ + idx];
      // DIRECTIONS in torch-loop order: i outer, j mid, k inner, skipping (0,0,0)
      constexpr int DI[26] = {-1,-1,-1,-1,-1,-1,-1,-1,-1, 0,0,0,0,0,0,0,0, 1,1,1,1,1,1,1,1,1};
      constexpr int DJ[26] = {-1,-1,-1, 0,0,0, 1,1,1, -1,-1,-1, 0,0, 1,1,1, -1,-1,-1, 0,0,0, 1,1,1};
      constexpr int DK[26] = {-1,0,1, -1,0,1, -1,0,1, -1,0,1, -1,1, -1,0,1, -1,0,1, -1,0,1, -1,0,1};
      float klv[26], dst[26];
      float s = 0.f;
#pragma unroll
      for (int t = 0; t < 26; t++) {
        const int nd = dd + DI[t], nh = hh + DJ[t], nw = ww + DK[t];
        const bool inb = ((unsigned)nd < (unsigned)D_) && ((unsigned)nh < (unsigned)H_) &&
                         ((unsigned)nw < (unsigned)W_);
        const int nidx = (nd * H_ + nh) * W_ + nw;
        dst[t] = inb ? gdist[nidx] : 0.f;
        // coordinate masks from the reference's (batch,d,h) indexing bug, specialized to B=1:
        //  i==+1 -> 0 (batch never 47); j==+1 -> 0 (d never 159); j==-1 -> only d==0;
        //  k==+1 -> only h==159; k==-1 -> only h==0
        bool keep;
        if (DI[t] == 1 || DJ[t] == 1) keep = false;
        else {
          keep = true;
          if (DJ[t] == -1) keep = (dd == 0);
          if (DK[t] == 1) keep = keep && (hh == H_ - 1);
          if (DK[t] == -1) keep = keep && (hh == 0);
        }
        float kt = 0.f;
        if (keep) {
          float t0 = 0.f, t1 = 0.f;
          if (inb) { t0 = inp[nidx]; t1 = inp[N_ + nidx]; }
          const float a0 = (t0 > 0.f) ? t0 * logf(t0) : 0.f;
          const float a1 = (t1 > 0.f) ? t1 * logf(t1) : 0.f;
          const float kldm = 0.5f * ((a0 - t0 * p0) + (a1 - t1 * p1));
          kt = expf(kldm);
        }
        klv[t] = kt;
        s += kt;
      }
      const float denom = (s == 0.f) ? 1.f : s;
      int amin = 0;
      float dmin = dst[0];
#pragma unroll
      for (int t = 1; t < 26; t++) {
        if (dst[t] < dmin) { dmin = dst[t]; amin = t; }  // first-min, like jnp.argmin
      }
      const float yoff = (float)(0.2 / 26.0);
      float bsum = 0.f;
#pragma unroll
      for (int t = 0; t < 26; t++) {
        const float x = klv[t] / denom;
        const float y = (t == amin) ? 0.8f : yoff;
        bsum += fmaxf(x, 0.f) - x * y + log1pf(expf(-fabsf(x)));
      }
      myloss = (fminf(g, 20.f) / 20.f) * (bsum / 26.f);
    }
  }
  __shared__ float ls[256];
  __shared__ unsigned lc[256];
  ls[tid] = myloss;
  lc[tid] = mycnt;
  __syncthreads();
  for (int o = 128; o > 0; o >>= 1) {
    if (tid < o) { ls[tid] += ls[tid + o]; lc[tid] += lc[tid + o]; }
    __syncthreads();
  }
  if (tid == 0) { psum[blockIdx.x] = ls[0]; pcnt[blockIdx.x] = lc[0]; }
}

// ---------------- deterministic final reduce ----------------
__global__ __launch_bounds__(256) void k_reduce(const float* __restrict__ psum,
                                                const unsigned* __restrict__ pcnt,
                                                float* __restrict__ out) {
  __shared__ float ls[256];
  __shared__ unsigned lc[256];
  const int t = threadIdx.x;
  float s = 0.f;
  unsigned c = 0;
  for (int i = t; i < NBLK; i += 256) { s += psum[i]; c += pcnt[i]; }
  ls[t] = s;
  lc[t] = c;
  __syncthreads();
  for (int o = 128; o > 0; o >>= 1) {
    if (t < o) { ls[t] += ls[t + o]; lc[t] += lc[t + o]; }
    __syncthreads();
  }
  if (t == 0) out[0] = ls[0] / (float)lc[0];
}

extern "C" void kernel_launch(void* const* d_in, const int* in_sizes, int n_in,
                              void* d_out, int out_size, void* d_ws, size_t ws_size,
                              hipStream_t stream) {
  (void)in_sizes; (void)n_in; (void)out_size; (void)ws_size;
  const float* inp = (const float*)d_in[0];
  const int* tgt = (const int*)d_in[1];
  float* out = (float*)d_out;
  char* ws = (char*)d_ws;

  float* kl = (float*)(ws + OFF_KL);
  float* fA = (float*)(ws + OFF_FA);
  float* fB = (float*)(ws + OFF_FB);
  unsigned* g1 = (unsigned*)(ws + OFF_G1);
  unsigned* g2 = (unsigned*)(ws + OFF_G2);
  unsigned* g3 = (unsigned*)(ws + OFF_G3);
  unsigned* sc = (unsigned*)(ws + OFF_SC);
  float* ps = (float*)(ws + OFF_PS);
  unsigned* pc = (unsigned*)(ws + OFF_PC);

  hipMemsetAsync(g1, 0, ZERO_BYTES, stream);  // g1,g2,g3,sc contiguous

  k_prep<<<HBLK, 256, 0, stream>>>(inp, tgt, kl, fA, g1);

  // EDT: three early-exit axis passes (bit-exact vs brute force)
  k_dt<HW_, D_, 0, false><<<NBLK, 256, 0, stream>>>(fA, fB);
  k_dt<W_, H_, 1, false><<<NBLK, 256, 0, stream>>>(fB, fA);
  k_dt<1, W_, 2, true><<<NBLK, 256, 0, stream>>>(fA, fB);  // fB = gdb_dist

  // 12+12+8 radix select for the 0.99-quantile order statistic
  k_sel<<<1, 256, 0, stream>>>(g1, 4096, nullptr, K1_, sc + 0, sc + 1);
  k_hist2<<<HBLK, 256, 0, stream>>>(kl, sc, g2);
  k_sel<<<1, 256, 0, stream>>>(g2, 4096, sc + 1, 0u, sc + 2, sc + 3);
  k_hist3<<<HBLK, 256, 0, stream>>>(kl, sc, g3);
  k_sel<<<1, 256, 0, stream>>>(g3, 256, sc + 3, 0u, sc + 4, sc + 5);
  k_thr<<<1, 1, 0, stream>>>(sc);

  k_loss<<<NBLK, 256, 0, stream>>>(inp, kl, fB, sc, ps, pc);
  k_reduce<<<1, 256, 0, stream>>>(ps, pc, out);
}